// Round 10
// baseline (692.961 us; speedup 1.0000x reference)
//
#include <hip/hip_runtime.h>
#include <hip/hip_bf16.h>
#include <cstddef>
#include <cstdint>

typedef __attribute__((ext_vector_type(4))) __bf16 bf16x4;
typedef __attribute__((ext_vector_type(8))) __bf16 bf16x8;
typedef __attribute__((ext_vector_type(4))) float f32x4;

#define L_SEQ 2048
#define KD 768
#define N_HEAD 12
#define NB 4
#define NX 8192          // B*L
#define NALL 49152       // B*L*(1+5)
#define KVLD 1536        // merged K|V output row length

// ---------------- weight fp32 -> bf16 ----------------
__global__ __launch_bounds__(256) void wconv_kernel(
    const float* __restrict__ W0, const float* __restrict__ W1,
    const float* __restrict__ W2, const float* __restrict__ W3,
    __bf16* __restrict__ O0, __bf16* __restrict__ O1,
    __bf16* __restrict__ O2, __bf16* __restrict__ O3)
{
    const float* src; __bf16* dst;
    switch (blockIdx.y) {
        case 0: src = W0; dst = O0; break;
        case 1: src = W1; dst = O1; break;
        case 2: src = W2; dst = O2; break;
        default: src = W3; dst = O3; break;
    }
    const int i = (blockIdx.x * 256 + threadIdx.x) * 4;
    const float4 v = *(const float4*)(src + i);
    bf16x4 t;
    t[0] = (__bf16)v.x; t[1] = (__bf16)v.y; t[2] = (__bf16)v.z; t[3] = (__bf16)v.w;
    *(bf16x4*)(dst + i) = t;
}

// ------------- convert+transpose into XT[n'(49152)][768] -------------
__global__ __launch_bounds__(256) void xconv_kernel(
    const float* __restrict__ x, const float* __restrict__ ax,
    __bf16* __restrict__ XT)
{
    __shared__ __bf16 S[64][72];
    const int t = threadIdx.x;
    const int ap = blockIdx.x >> 7;
    const int inner = blockIdx.x & 127;
    const int bb = inner >> 5;
    const int l0 = (inner & 31) * 64;
    const int d0 = blockIdx.y * 64;
    const int r = t >> 4;
    const int c4 = (t & 15) * 4;
    #pragma unroll
    for (int p = 0; p < 4; ++p) {
        const int d = d0 + r + p * 16;
        const float* src = (ap == 0)
            ? x + ((size_t)(bb * KD + d)) * L_SEQ
            : ax + (((size_t)(bb * KD + d)) * 5 + (ap - 1)) * L_SEQ;
        const float4 v = *(const float4*)(src + l0 + c4);
        S[c4 + 0][r + p * 16] = (__bf16)v.x;
        S[c4 + 1][r + p * 16] = (__bf16)v.y;
        S[c4 + 2][r + p * 16] = (__bf16)v.z;
        S[c4 + 3][r + p * 16] = (__bf16)v.w;
    }
    __syncthreads();
    #pragma unroll
    for (int p = 0; p < 4; ++p) {
        const int lr = r + p * 16;
        const bf16x4 v = *(const bf16x4*)&S[lr][c4];
        *(bf16x4*)(XT + ((size_t)ap * NX + bb * L_SEQ + l0 + lr) * KD + d0 + c4) = v;
    }
}

// ============ register-direct "flatmm" GEMM core ============
// Block: 256 thr = 4 waves. Tile: 128 m x 256 n; wave wv owns n-cols wv*64..+63.
// acc[8][4]: m = i*16 + (lane>>4)*4 + r, n(local64) = j*16 + (lane&15).
// Per K-step t (24 total, fully unrolled): 8 A-frag + 4 B-frag 16B global loads
// per lane (full-64B-sector coverage per wave), 32 MFMA. No LDS staging, no
// barriers -> compiler pipelines loads across steps; 8 waves/CU TLP.
__device__ __forceinline__ void gemm_core(
    const __bf16* __restrict__ pA, const __bf16* __restrict__ pB, f32x4 (&acc)[8][4])
{
    #pragma unroll
    for (int t = 0; t < 24; ++t) {
        bf16x8 a[8], b[4];
        #pragma unroll
        for (int i = 0; i < 8; ++i)
            a[i] = *(const bf16x8*)(pA + (size_t)(i * 16) * KD + t * 32);
        #pragma unroll
        for (int j = 0; j < 4; ++j)
            b[j] = *(const bf16x8*)(pB + (size_t)(j * 16) * KD + t * 32);
        #pragma unroll
        for (int i = 0; i < 8; ++i)
            #pragma unroll
            for (int j = 0; j < 4; ++j)
                acc[i][j] = __builtin_amdgcn_mfma_f32_16x16x32_bf16(a[i], b[j], acc[i][j], 0, 0, 0);
    }
}

// ---------------- merged Q|K|V projection ----------------
// Wall = [Wq;Wk;Wv] (2304x768). Grid 3456 (=8*432): XCD-chunked; nb=gidx/18,
// mb=gidx%18. ap=0 tiles use all 18 m-blocks (Q+K+V); ap>=1 use 12 (K,V only).
// Qt[8192][768]; KVt[49152][1536].
__global__ __launch_bounds__(256, 2) void gemm_kvq(
    const __bf16* __restrict__ Wall,
    const float* __restrict__ bq, const float* __restrict__ bk, const float* __restrict__ bv,
    const __bf16* __restrict__ XT, __bf16* __restrict__ Qt, __bf16* __restrict__ KVt)
{
    __shared__ __bf16 T[4][2176];
    const int bid = blockIdx.x;
    const int gidx = (bid & 7) * 432 + (bid >> 3);
    const int nb = gidx / 18, mb = gidx % 18;
    const int n0 = nb * 256;
    const bool cross = (n0 >= NX);
    if (cross && mb >= 12) return;
    const int mrow = cross ? (768 + mb * 128) : (mb * 128);

    const int tid = threadIdx.x;
    const int lane = tid & 63, wv = tid >> 6;
    const int lr = lane & 15, kslc = lane >> 4;

    const __bf16* pA = Wall + (size_t)(mrow + lr) * KD + kslc * 8;
    const __bf16* pB = XT + (size_t)(n0 + wv * 64 + lr) * KD + kslc * 8;

    f32x4 acc[8][4];
    #pragma unroll
    for (int i = 0; i < 8; ++i)
        #pragma unroll
        for (int j = 0; j < 4; ++j)
            acc[i][j] = (f32x4){0.f, 0.f, 0.f, 0.f};

    gemm_core(pA, pB, acc);

    // epilogue: bias + transpose via per-wave private LDS, 16B stores
    __bf16* outp; int ldo, mcol;
    if (mrow < 768) { outp = Qt; ldo = KD; mcol = mrow; }
    else            { outp = KVt; ldo = KVLD; mcol = mrow - 768; }

    const int row0 = kslc * 4;
    const int rr = lane >> 2, seg = lane & 3;
    #pragma unroll
    for (int j = 0; j < 4; ++j) {
        #pragma unroll
        for (int i = 0; i < 8; ++i) {
            bf16x4 v;
            #pragma unroll
            for (int r = 0; r < 4; ++r) {
                const int mg = mrow + i * 16 + row0 + r;
                const float bb = (mg < 768) ? bq[mg] : (mg < 1536 ? bk[mg - 768] : bv[mg - 1536]);
                v[r] = (__bf16)(acc[i][j][r] + bb);
            }
            *(bf16x4*)(&T[wv][lr * 136 + i * 16 + row0]) = v;
        }
        __bf16* dst = outp + (size_t)(n0 + wv * 64 + j * 16 + rr) * ldo + mcol + seg * 32;
        const __bf16* src = &T[wv][rr * 136 + seg * 32];
        #pragma unroll
        for (int s = 0; s < 4; ++s)
            *(bf16x8*)(dst + s * 8) = *(const bf16x8*)(src + s * 8);
    }
}

// ---------------- O projection (fp32 final out) ----------------
// Wo [768][768], B = attT [8192][768]. Grid 192 (=8*24): mb=gidx%6, nb=gidx/6.
__global__ __launch_bounds__(256, 2) void gemm_o(
    const __bf16* __restrict__ Wo, const float* __restrict__ bo,
    const __bf16* __restrict__ attT, float* __restrict__ out)
{
    const int bid = blockIdx.x;
    const int gidx = (bid & 7) * 24 + (bid >> 3);
    const int mb = gidx % 6, nb = gidx / 6;
    const int m0 = mb * 128, n0 = nb * 256;

    const int tid = threadIdx.x;
    const int lane = tid & 63, wv = tid >> 6;
    const int lr = lane & 15, kslc = lane >> 4;

    const __bf16* pA = Wo + (size_t)(m0 + lr) * KD + kslc * 8;
    const __bf16* pB = attT + (size_t)(n0 + wv * 64 + lr) * KD + kslc * 8;

    f32x4 acc[8][4];
    #pragma unroll
    for (int i = 0; i < 8; ++i)
        #pragma unroll
        for (int j = 0; j < 4; ++j)
            acc[i][j] = (f32x4){0.f, 0.f, 0.f, 0.f};

    gemm_core(pA, pB, acc);

    const int row0 = kslc * 4;
    const int b_ = n0 >> 11;
    const int l0 = (n0 & 2047) + wv * 64;
    #pragma unroll
    for (int i = 0; i < 8; ++i)
        #pragma unroll
        for (int r = 0; r < 4; ++r) {
            const int mg = m0 + i * 16 + row0 + r;
            const float bb = bo[mg];
            #pragma unroll
            for (int j = 0; j < 4; ++j)
                out[((size_t)(b_ * KD + mg)) * L_SEQ + l0 + j * 16 + lr] = acc[i][j][r] + bb;
        }
}

// ---------------- attention (transposed, 16B loads) ----------------
// Qt: [8192][768]; KVt: [49152][1536] (K at +0, V at +768); attT: [8192][768]
__global__ __launch_bounds__(256) void attn_kernel(
    const __bf16* __restrict__ Qt, const __bf16* __restrict__ KVt,
    __bf16* __restrict__ attT)
{
    const int bid = blockIdx.x;
    const int lt = bid & 63;
    const int h = bid >> 6;
    const int tid = threadIdx.x;
    const int wave = tid >> 6, lane = tid & 63;
    const int half = lane >> 5, ln = lane & 31;
    const int n = lt * 128 + wave * 32 + ln;
    const int l = n & (L_SEQ - 1);
    const int c0 = h * 64 + half * 32;

    float q[32];
    {
        const __bf16* qp = Qt + (size_t)n * KD + c0;
        #pragma unroll
        for (int s = 0; s < 4; ++s) {
            const bf16x8 v = *(const bf16x8*)(qp + s * 8);
            #pragma unroll
            for (int j = 0; j < 8; ++j) q[s * 8 + j] = (float)v[j];
        }
    }

    float sc[10];
    #pragma unroll
    for (int w = 0; w < 5; ++w) {
        const int lw = l + w - 2;
        float acc = 0.f;
        if ((unsigned)lw < L_SEQ) {
            const __bf16* kp = KVt + (size_t)(n + w - 2) * KVLD + c0;
            #pragma unroll
            for (int s = 0; s < 4; ++s) {
                const bf16x8 v = *(const bf16x8*)(kp + s * 8);
                #pragma unroll
                for (int j = 0; j < 8; ++j) acc += q[s * 8 + j] * (float)v[j];
            }
        }
        sc[w] = acc;
    }
    #pragma unroll
    for (int a = 0; a < 5; ++a) {
        const __bf16* kp = KVt + ((size_t)(a + 1) * NX + n) * KVLD + c0;
        float acc = 0.f;
        #pragma unroll
        for (int s = 0; s < 4; ++s) {
            const bf16x8 v = *(const bf16x8*)(kp + s * 8);
            #pragma unroll
            for (int j = 0; j < 8; ++j) acc += q[s * 8 + j] * (float)v[j];
        }
        sc[5 + a] = acc;
    }

    #pragma unroll
    for (int i = 0; i < 10; ++i) {
        sc[i] += __shfl_xor(sc[i], 32);
        sc[i] *= 0.125f;
    }

    float mx = sc[0];
    #pragma unroll
    for (int i = 1; i < 10; ++i) mx = fmaxf(mx, sc[i]);
    float e[10], sum = 0.f;
    #pragma unroll
    for (int i = 0; i < 10; ++i) { e[i] = __expf(sc[i] - mx); sum += e[i]; }
    const float inv = 1.f / sum;

    float o[32];
    #pragma unroll
    for (int i = 0; i < 32; ++i) o[i] = 0.f;

    #pragma unroll
    for (int w = 0; w < 5; ++w) {
        const int lw = l + w - 2;
        if ((unsigned)lw < L_SEQ) {
            const __bf16* vp = KVt + (size_t)(n + w - 2) * KVLD + 768 + c0;
            #pragma unroll
            for (int s = 0; s < 4; ++s) {
                const bf16x8 v = *(const bf16x8*)(vp + s * 8);
                #pragma unroll
                for (int j = 0; j < 8; ++j) o[s * 8 + j] += e[w] * (float)v[j];
            }
        }
    }
    #pragma unroll
    for (int a = 0; a < 5; ++a) {
        const __bf16* vp = KVt + ((size_t)(a + 1) * NX + n) * KVLD + 768 + c0;
        #pragma unroll
        for (int s = 0; s < 4; ++s) {
            const bf16x8 v = *(const bf16x8*)(vp + s * 8);
            #pragma unroll
            for (int j = 0; j < 8; ++j) o[s * 8 + j] += e[5 + a] * (float)v[j];
        }
    }

    __bf16* dst = attT + (size_t)n * KD + c0;
    #pragma unroll
    for (int s = 0; s < 4; ++s) {
        bf16x8 t;
        #pragma unroll
        for (int j = 0; j < 8; ++j) t[j] = (__bf16)(o[s * 8 + j] * inv);
        *(bf16x8*)(dst + s * 8) = t;
    }
}

extern "C" void kernel_launch(void* const* d_in, const int* in_sizes, int n_in,
                              void* d_out, int out_size, void* d_ws, size_t ws_size,
                              hipStream_t stream)
{
    const float* x  = (const float*)d_in[0];
    const float* ax = (const float*)d_in[1];
    const float* Wq = (const float*)d_in[2];
    const float* bq = (const float*)d_in[3];
    const float* Wk = (const float*)d_in[4];
    const float* bk = (const float*)d_in[5];
    const float* Wv = (const float*)d_in[6];
    const float* bv = (const float*)d_in[7];
    const float* Wo = (const float*)d_in[8];
    const float* bo = (const float*)d_in[9];
    float* out = (float*)d_out;

    __bf16* p = (__bf16*)d_ws;
    __bf16* Wall  = p;                        // [Wq;Wk;Wv] contiguous (2304x768)
    __bf16* Wq_bf = p; p += 589824;
    __bf16* Wk_bf = p; p += 589824;
    __bf16* Wv_bf = p; p += 589824;
    __bf16* Wo_bf = p; p += 589824;
    __bf16* Qt    = p; p += (size_t)KD * NX;
    __bf16* KVt   = p; p += (size_t)KVLD * NALL;
    __bf16* XT    = p; p += (size_t)KD * NALL;
    __bf16* attT  = p;

    wconv_kernel<<<dim3(576, 4), dim3(256), 0, stream>>>(Wq, Wk, Wv, Wo, Wq_bf, Wk_bf, Wv_bf, Wo_bf);
    xconv_kernel<<<dim3(768, 12), dim3(256), 0, stream>>>(x, ax, XT);

    // merged Q|K|V: 192 n-tiles x 18 m-blocks (12 for cross tiles) = 3456 slots
    gemm_kvq<<<dim3(3456), dim3(256), 0, stream>>>(Wall, bq, bk, bv, XT, Qt, KVt);

    attn_kernel<<<dim3(64 * N_HEAD), dim3(256), 0, stream>>>(Qt, KVt, attT);

    gemm_o<<<dim3(192), dim3(256), 0, stream>>>(Wo_bf, bo, attT, out);
}

// Round 11
// 302.329 us; speedup vs baseline: 2.2921x; 2.2921x over previous
//
#include <hip/hip_runtime.h>
#include <hip/hip_bf16.h>
#include <cstddef>
#include <cstdint>

typedef __attribute__((ext_vector_type(4))) __bf16 bf16x4;
typedef __attribute__((ext_vector_type(8))) __bf16 bf16x8;
typedef __attribute__((ext_vector_type(4))) float f32x4;

#define L_SEQ 2048
#define KD 768
#define N_HEAD 12
#define NB 4
#define NX 8192          // B*L
#define NALL 49152       // B*L*(1+5)
#define KVLD 1536        // merged K|V output row length

__device__ __forceinline__ void gload16(const __bf16* g, __bf16* l) {
    __builtin_amdgcn_global_load_lds(
        (const __attribute__((address_space(1))) void*)g,
        (__attribute__((address_space(3))) void*)l, 16, 0, 0);
}

// ---------------- weight fp32 -> bf16 ----------------
__global__ __launch_bounds__(256) void wconv_kernel(
    const float* __restrict__ W0, const float* __restrict__ W1,
    const float* __restrict__ W2, const float* __restrict__ W3,
    __bf16* __restrict__ O0, __bf16* __restrict__ O1,
    __bf16* __restrict__ O2, __bf16* __restrict__ O3)
{
    const float* src; __bf16* dst;
    switch (blockIdx.y) {
        case 0: src = W0; dst = O0; break;
        case 1: src = W1; dst = O1; break;
        case 2: src = W2; dst = O2; break;
        default: src = W3; dst = O3; break;
    }
    const int i = (blockIdx.x * 256 + threadIdx.x) * 4;
    const float4 v = *(const float4*)(src + i);
    bf16x4 t;
    t[0] = (__bf16)v.x; t[1] = (__bf16)v.y; t[2] = (__bf16)v.z; t[3] = (__bf16)v.w;
    *(bf16x4*)(dst + i) = t;
}

// ------------- convert+transpose into XT[n'(49152)][768] -------------
__global__ __launch_bounds__(256) void xconv_kernel(
    const float* __restrict__ x, const float* __restrict__ ax,
    __bf16* __restrict__ XT)
{
    __shared__ __bf16 S[64][72];
    const int t = threadIdx.x;
    const int ap = blockIdx.x >> 7;
    const int inner = blockIdx.x & 127;
    const int bb = inner >> 5;
    const int l0 = (inner & 31) * 64;
    const int d0 = blockIdx.y * 64;
    const int r = t >> 4;
    const int c4 = (t & 15) * 4;
    #pragma unroll
    for (int p = 0; p < 4; ++p) {
        const int d = d0 + r + p * 16;
        const float* src = (ap == 0)
            ? x + ((size_t)(bb * KD + d)) * L_SEQ
            : ax + (((size_t)(bb * KD + d)) * 5 + (ap - 1)) * L_SEQ;
        const float4 v = *(const float4*)(src + l0 + c4);
        S[c4 + 0][r + p * 16] = (__bf16)v.x;
        S[c4 + 1][r + p * 16] = (__bf16)v.y;
        S[c4 + 2][r + p * 16] = (__bf16)v.z;
        S[c4 + 3][r + p * 16] = (__bf16)v.w;
    }
    __syncthreads();
    #pragma unroll
    for (int p = 0; p < 4; ++p) {
        const int lr = r + p * 16;
        const bf16x4 v = *(const bf16x4*)&S[lr][c4];
        *(bf16x4*)(XT + ((size_t)ap * NX + bb * L_SEQ + l0 + lr) * KD + d0 + c4) = v;
    }
}

// ---------------- m97-structure 128x128 GEMM (R2-proven: ~850-1000 TF here) ----------------
// Out = A[M][768] * Bt[N][768]^T + bias. 256 thr = 4 waves (2x2 of 64x64),
// acc[4][4], single-buffered 32KB LDS, 2 barriers/step, gload_lds(16B), linear
// LDS layout (conflicts known-benign in this structure, m98/R4 evidence).
// Small footprint -> 2-3 blocks/CU: independent barrier domains provide the
// latency-hiding TLP the 256-tile variants lacked (m114 mechanism).
template <int MODE>   // 0: bf16 OutT[n'][ldo], col m0; 1: fp32 out[(b*768+m)*2048+l]
__device__ __forceinline__ void gemm_body(
    const __bf16* __restrict__ A, const __bf16* __restrict__ Bt,
    const float* __restrict__ bias_lo, const float* __restrict__ bias_hi,
    void* __restrict__ Out, int ldo, int m0, int n0, __bf16* LDS)
{
    __bf16* As = LDS;
    __bf16* Bs = LDS + 8192;
    const int tid = threadIdx.x;
    const int lane = tid & 63, wave = tid >> 6;
    const int wr = (wave >> 1) * 64, wc = (wave & 1) * 64;
    const int lr = lane & 15, lk = (lane >> 4) * 8;
    const int srow = lane >> 3;
    const int skq = (lane & 7) * 8;

    f32x4 acc[4][4];
    #pragma unroll
    for (int i = 0; i < 4; ++i)
        #pragma unroll
        for (int j = 0; j < 4; ++j)
            acc[i][j] = (f32x4){0.f, 0.f, 0.f, 0.f};

    for (int kt = 0; kt < KD; kt += 64) {
        __syncthreads();
        #pragma unroll
        for (int p = 0; p < 4; ++p) {
            const int rb = wave * 32 + p * 8;
            gload16(A  + (size_t)(m0 + rb + srow) * KD + kt + skq, As + rb * 64);
            gload16(Bt + (size_t)(n0 + rb + srow) * KD + kt + skq, Bs + rb * 64);
        }
        __syncthreads();
        #pragma unroll
        for (int ks = 0; ks < 2; ++ks) {
            const int ko = ks * 32 + lk;
            bf16x8 a[4], b[4];
            #pragma unroll
            for (int f = 0; f < 4; ++f) a[f] = *(const bf16x8*)(As + (wr + f * 16 + lr) * 64 + ko);
            #pragma unroll
            for (int f = 0; f < 4; ++f) b[f] = *(const bf16x8*)(Bs + (wc + f * 16 + lr) * 64 + ko);
            #pragma unroll
            for (int i = 0; i < 4; ++i)
                #pragma unroll
                for (int j = 0; j < 4; ++j)
                    acc[i][j] = __builtin_amdgcn_mfma_f32_16x16x32_bf16(a[i], b[j], acc[i][j], 0, 0, 0);
        }
    }

    const int row0 = (lane >> 4) * 4;   // C/D: col=lane&15 (n), row=(lane>>4)*4+reg (m)

    if (MODE == 0) {
        // transpose via LDS (reuse staging region), then coalesced 16B writes
        __syncthreads();
        #pragma unroll
        for (int i = 0; i < 4; ++i) {
            #pragma unroll
            for (int r = 0; r < 4; ++r) {
                const int mm = wr + i * 16 + row0 + r;
                const int mg = m0 + mm;
                const float bi = (mg < 768) ? bias_lo[mg] : bias_hi[mg - 768];
                #pragma unroll
                for (int j = 0; j < 4; ++j) {
                    const int nl = wc + j * 16 + lr;
                    LDS[nl * 136 + mm] = (__bf16)(acc[i][j][r] + bi);
                }
            }
        }
        __syncthreads();
        __bf16* OutT = (__bf16*)Out;
        const int rown = tid >> 1;
        const int coff = (tid & 1) * 64;
        #pragma unroll
        for (int s = 0; s < 8; ++s) {
            const bf16x8 v = *(const bf16x8*)(LDS + rown * 136 + coff + s * 8);
            *(bf16x8*)(OutT + (size_t)(n0 + rown) * ldo + m0 + coff + s * 8) = v;
        }
    } else {
        #pragma unroll
        for (int i = 0; i < 4; ++i) {
            #pragma unroll
            for (int r = 0; r < 4; ++r) {
                const int mg = m0 + wr + i * 16 + row0 + r;
                const float bi = bias_lo[mg];
                #pragma unroll
                for (int j = 0; j < 4; ++j) {
                    const int nl = wc + j * 16 + lr;
                    const int b_ = n0 >> 11, lo = (n0 & 2047) + nl;
                    ((float*)Out)[((size_t)(b_ * KD + mg)) * L_SEQ + lo] = acc[i][j][r] + bi;
                }
            }
        }
    }
}

// merged K|V: A = [Wk;Wv] (1536x768). Grid 4608 = 12 m-tiles x 384 n-tiles,
// XCD-grouped (4608/8=576), m-fast so same-n-panel blocks share an XCD's L2.
__global__ __launch_bounds__(256, 2) void gemm_kv(
    const __bf16* __restrict__ Wkv, const float* __restrict__ bk, const float* __restrict__ bv,
    const __bf16* __restrict__ XT, __bf16* __restrict__ KVt)
{
    __shared__ __bf16 LDS[17408];
    const int bid = blockIdx.x;
    const int gidx = (bid & 7) * 576 + (bid >> 3);
    const int m0 = (gidx % 12) * 128;
    const int n0 = (gidx / 12) * 128;
    gemm_body<0>(Wkv, XT, bk, bv, KVt, KVLD, m0, n0, LDS);
}

template <int MODE, int NM>
__global__ __launch_bounds__(256, 2) void gemm_one(
    const __bf16* __restrict__ W, const float* __restrict__ bias,
    const __bf16* __restrict__ Bt, void* __restrict__ Out, int ldo)
{
    __shared__ __bf16 LDS[17408];
    const int bid = blockIdx.x;
    const int nwg8 = gridDim.x >> 3;
    const int gidx = (bid & 7) * nwg8 + (bid >> 3);
    const int m0 = (gidx % NM) * 128;
    const int n0 = (gidx / NM) * 128;
    gemm_body<MODE>(W, Bt, bias, bias, Out, ldo, m0, n0, LDS);
}

// ---------------- attention (transposed, 16B loads) ----------------
// Qt: [8192][768]; KVt: [49152][1536] (K at +0, V at +768); attT: [8192][768]
__global__ __launch_bounds__(256) void attn_kernel(
    const __bf16* __restrict__ Qt, const __bf16* __restrict__ KVt,
    __bf16* __restrict__ attT)
{
    const int bid = blockIdx.x;
    const int lt = bid & 63;
    const int h = bid >> 6;
    const int tid = threadIdx.x;
    const int wave = tid >> 6, lane = tid & 63;
    const int half = lane >> 5, ln = lane & 31;
    const int n = lt * 128 + wave * 32 + ln;
    const int l = n & (L_SEQ - 1);
    const int c0 = h * 64 + half * 32;

    float q[32];
    {
        const __bf16* qp = Qt + (size_t)n * KD + c0;
        #pragma unroll
        for (int s = 0; s < 4; ++s) {
            const bf16x8 v = *(const bf16x8*)(qp + s * 8);
            #pragma unroll
            for (int j = 0; j < 8; ++j) q[s * 8 + j] = (float)v[j];
        }
    }

    float sc[10];
    #pragma unroll
    for (int w = 0; w < 5; ++w) {
        const int lw = l + w - 2;
        float acc = 0.f;
        if ((unsigned)lw < L_SEQ) {
            const __bf16* kp = KVt + (size_t)(n + w - 2) * KVLD + c0;
            #pragma unroll
            for (int s = 0; s < 4; ++s) {
                const bf16x8 v = *(const bf16x8*)(kp + s * 8);
                #pragma unroll
                for (int j = 0; j < 8; ++j) acc += q[s * 8 + j] * (float)v[j];
            }
        }
        sc[w] = acc;
    }
    #pragma unroll
    for (int a = 0; a < 5; ++a) {
        const __bf16* kp = KVt + ((size_t)(a + 1) * NX + n) * KVLD + c0;
        float acc = 0.f;
        #pragma unroll
        for (int s = 0; s < 4; ++s) {
            const bf16x8 v = *(const bf16x8*)(kp + s * 8);
            #pragma unroll
            for (int j = 0; j < 8; ++j) acc += q[s * 8 + j] * (float)v[j];
        }
        sc[5 + a] = acc;
    }

    #pragma unroll
    for (int i = 0; i < 10; ++i) {
        sc[i] += __shfl_xor(sc[i], 32);
        sc[i] *= 0.125f;
    }

    float mx = sc[0];
    #pragma unroll
    for (int i = 1; i < 10; ++i) mx = fmaxf(mx, sc[i]);
    float e[10], sum = 0.f;
    #pragma unroll
    for (int i = 0; i < 10; ++i) { e[i] = __expf(sc[i] - mx); sum += e[i]; }
    const float inv = 1.f / sum;

    float o[32];
    #pragma unroll
    for (int i = 0; i < 32; ++i) o[i] = 0.f;

    #pragma unroll
    for (int w = 0; w < 5; ++w) {
        const int lw = l + w - 2;
        if ((unsigned)lw < L_SEQ) {
            const __bf16* vp = KVt + (size_t)(n + w - 2) * KVLD + 768 + c0;
            #pragma unroll
            for (int s = 0; s < 4; ++s) {
                const bf16x8 v = *(const bf16x8*)(vp + s * 8);
                #pragma unroll
                for (int j = 0; j < 8; ++j) o[s * 8 + j] += e[w] * (float)v[j];
            }
        }
    }
    #pragma unroll
    for (int a = 0; a < 5; ++a) {
        const __bf16* vp = KVt + ((size_t)(a + 1) * NX + n) * KVLD + 768 + c0;
        #pragma unroll
        for (int s = 0; s < 4; ++s) {
            const bf16x8 v = *(const bf16x8*)(vp + s * 8);
            #pragma unroll
            for (int j = 0; j < 8; ++j) o[s * 8 + j] += e[5 + a] * (float)v[j];
        }
    }

    __bf16* dst = attT + (size_t)n * KD + c0;
    #pragma unroll
    for (int s = 0; s < 4; ++s) {
        bf16x8 t;
        #pragma unroll
        for (int j = 0; j < 8; ++j) t[j] = (__bf16)(o[s * 8 + j] * inv);
        *(bf16x8*)(dst + s * 8) = t;
    }
}

extern "C" void kernel_launch(void* const* d_in, const int* in_sizes, int n_in,
                              void* d_out, int out_size, void* d_ws, size_t ws_size,
                              hipStream_t stream)
{
    const float* x  = (const float*)d_in[0];
    const float* ax = (const float*)d_in[1];
    const float* Wq = (const float*)d_in[2];
    const float* bq = (const float*)d_in[3];
    const float* Wk = (const float*)d_in[4];
    const float* bk = (const float*)d_in[5];
    const float* Wv = (const float*)d_in[6];
    const float* bv = (const float*)d_in[7];
    const float* Wo = (const float*)d_in[8];
    const float* bo = (const float*)d_in[9];
    float* out = (float*)d_out;

    __bf16* p = (__bf16*)d_ws;
    __bf16* Wq_bf = p; p += 589824;
    __bf16* Wkv_bf = p;                       // [Wk_bf; Wv_bf] contiguous
    __bf16* Wk_bf = p; p += 589824;
    __bf16* Wv_bf = p; p += 589824;
    __bf16* Wo_bf = p; p += 589824;
    __bf16* Qt    = p; p += (size_t)KD * NX;
    __bf16* KVt   = p; p += (size_t)KVLD * NALL;
    __bf16* XT    = p; p += (size_t)KD * NALL;
    __bf16* attT  = p;

    wconv_kernel<<<dim3(576, 4), dim3(256), 0, stream>>>(Wq, Wk, Wv, Wo, Wq_bf, Wk_bf, Wv_bf, Wo_bf);
    xconv_kernel<<<dim3(768, 12), dim3(256), 0, stream>>>(x, ax, XT);

    // KV merged: 12 m-tiles x 384 n-tiles = 4608 blocks (128x128 each)
    gemm_kv<<<dim3(4608), dim3(256), 0, stream>>>(Wkv_bf, bk, bv, XT, KVt);
    // Q: 6 m x 64 n = 384 blocks
    gemm_one<0, 6><<<dim3(384), dim3(256), 0, stream>>>(Wq_bf, bq, XT, Qt, KD);

    attn_kernel<<<dim3(64 * N_HEAD), dim3(256), 0, stream>>>(Qt, KVt, attT);

    // O: fp32 final out
    gemm_one<1, 6><<<dim3(384), dim3(256), 0, stream>>>(Wo_bf, bo, attT, out, 0);
}

// Round 12
// 273.481 us; speedup vs baseline: 2.5338x; 1.1055x over previous
//
#include <hip/hip_runtime.h>
#include <hip/hip_bf16.h>
#include <cstddef>
#include <cstdint>

typedef __attribute__((ext_vector_type(4))) __bf16 bf16x4;
typedef __attribute__((ext_vector_type(8))) __bf16 bf16x8;
typedef __attribute__((ext_vector_type(4))) float f32x4;

#define L_SEQ 2048
#define KD 768
#define N_HEAD 12
#define NB 4
#define NX 8192          // B*L
#define NALL 49152       // B*L*(1+5)
#define KVLD 1536        // merged K|V output row length

__device__ __forceinline__ void gload16(const __bf16* g, __bf16* l) {
    __builtin_amdgcn_global_load_lds(
        (const __attribute__((address_space(1))) void*)g,
        (__attribute__((address_space(3))) void*)l, 16, 0, 0);
}

// ---------------- weight fp32 -> bf16 ----------------
__global__ __launch_bounds__(256) void wconv_kernel(
    const float* __restrict__ W0, const float* __restrict__ W1,
    const float* __restrict__ W2, const float* __restrict__ W3,
    __bf16* __restrict__ O0, __bf16* __restrict__ O1,
    __bf16* __restrict__ O2, __bf16* __restrict__ O3)
{
    const float* src; __bf16* dst;
    switch (blockIdx.y) {
        case 0: src = W0; dst = O0; break;
        case 1: src = W1; dst = O1; break;
        case 2: src = W2; dst = O2; break;
        default: src = W3; dst = O3; break;
    }
    const int i = (blockIdx.x * 256 + threadIdx.x) * 4;
    const float4 v = *(const float4*)(src + i);
    bf16x4 t;
    t[0] = (__bf16)v.x; t[1] = (__bf16)v.y; t[2] = (__bf16)v.z; t[3] = (__bf16)v.w;
    *(bf16x4*)(dst + i) = t;
}

// ------------- convert+transpose into XT[n'(49152)][768] -------------
__global__ __launch_bounds__(256) void xconv_kernel(
    const float* __restrict__ x, const float* __restrict__ ax,
    __bf16* __restrict__ XT)
{
    __shared__ __bf16 S[64][72];
    const int t = threadIdx.x;
    const int ap = blockIdx.x >> 7;
    const int inner = blockIdx.x & 127;
    const int bb = inner >> 5;
    const int l0 = (inner & 31) * 64;
    const int d0 = blockIdx.y * 64;
    const int r = t >> 4;
    const int c4 = (t & 15) * 4;
    #pragma unroll
    for (int p = 0; p < 4; ++p) {
        const int d = d0 + r + p * 16;
        const float* src = (ap == 0)
            ? x + ((size_t)(bb * KD + d)) * L_SEQ
            : ax + (((size_t)(bb * KD + d)) * 5 + (ap - 1)) * L_SEQ;
        const float4 v = *(const float4*)(src + l0 + c4);
        S[c4 + 0][r + p * 16] = (__bf16)v.x;
        S[c4 + 1][r + p * 16] = (__bf16)v.y;
        S[c4 + 2][r + p * 16] = (__bf16)v.z;
        S[c4 + 3][r + p * 16] = (__bf16)v.w;
    }
    __syncthreads();
    #pragma unroll
    for (int p = 0; p < 4; ++p) {
        const int lr = r + p * 16;
        const bf16x4 v = *(const bf16x4*)&S[lr][c4];
        *(bf16x4*)(XT + ((size_t)ap * NX + bb * L_SEQ + l0 + lr) * KD + d0 + c4) = v;
    }
}

// ---------------- m97-structure 128x128 GEMM + 8-slot XOR swizzle ----------------
// Out = A[M][768] * Bt[N][768]^T + bias. 256 thr = 4 waves (2x2 of 64x64),
// acc[4][4], single-buffered 32KB LDS, 2 barriers/step, gload_lds(16B).
// Bank-conflict fix (R11): row stride is 128B (zero bank entropy), so the raw
// layout is a 16-way conflict on every ds_read_b128 (R10: 4.4e7 conflict cyc).
// Involutive 8-slot XOR, both sides (rule #21):
//   stage: lane (srow=lane>>3, sk=lane&7) fetches global slot sk^srow
//          -> LDS[row][s] holds global slot s^(row&7)   (LDS dest stays linear)
//   read:  slot (ks*4+kslc) ^ (lr&7)  [row&7 == lr&7 since wr,f*16 are mult-16]
// 16-lane quarter-group -> slots s^0..s^7, 2 lanes/slot: 2-way = free (m136).
template <int MODE>   // 0: bf16 OutT[n'][ldo], col m0; 1: fp32 out[(b*768+m)*2048+l]
__device__ __forceinline__ void gemm_body(
    const __bf16* __restrict__ A, const __bf16* __restrict__ Bt,
    const float* __restrict__ bias_lo, const float* __restrict__ bias_hi,
    void* __restrict__ Out, int ldo, int m0, int n0, __bf16* LDS)
{
    __bf16* As = LDS;
    __bf16* Bs = LDS + 8192;
    const int tid = threadIdx.x;
    const int lane = tid & 63, wave = tid >> 6;
    const int wr = (wave >> 1) * 64, wc = (wave & 1) * 64;
    const int lr = lane & 15;
    const int kslc = lane >> 4;               // 0..3
    const int srow = lane >> 3;               // 0..7
    const int skq = ((lane & 7) ^ srow) * 8;  // pre-swizzled global k-slot

    f32x4 acc[4][4];
    #pragma unroll
    for (int i = 0; i < 4; ++i)
        #pragma unroll
        for (int j = 0; j < 4; ++j)
            acc[i][j] = (f32x4){0.f, 0.f, 0.f, 0.f};

    for (int kt = 0; kt < KD; kt += 64) {
        __syncthreads();
        #pragma unroll
        for (int p = 0; p < 4; ++p) {
            const int rb = wave * 32 + p * 8;
            gload16(A  + (size_t)(m0 + rb + srow) * KD + kt + skq, As + rb * 64);
            gload16(Bt + (size_t)(n0 + rb + srow) * KD + kt + skq, Bs + rb * 64);
        }
        __syncthreads();
        #pragma unroll
        for (int ks = 0; ks < 2; ++ks) {
            const int ko = ((ks * 4 + kslc) ^ (lr & 7)) * 8;   // swizzled read slot
            bf16x8 a[4], b[4];
            #pragma unroll
            for (int f = 0; f < 4; ++f) a[f] = *(const bf16x8*)(As + (wr + f * 16 + lr) * 64 + ko);
            #pragma unroll
            for (int f = 0; f < 4; ++f) b[f] = *(const bf16x8*)(Bs + (wc + f * 16 + lr) * 64 + ko);
            #pragma unroll
            for (int i = 0; i < 4; ++i)
                #pragma unroll
                for (int j = 0; j < 4; ++j)
                    acc[i][j] = __builtin_amdgcn_mfma_f32_16x16x32_bf16(a[i], b[j], acc[i][j], 0, 0, 0);
        }
    }

    const int row0 = kslc * 4;   // C/D: col=lane&15 (n), row=(lane>>4)*4+reg (m)

    if (MODE == 0) {
        // transpose via LDS (reuse staging region), then coalesced 16B writes
        __syncthreads();
        #pragma unroll
        for (int i = 0; i < 4; ++i) {
            #pragma unroll
            for (int r = 0; r < 4; ++r) {
                const int mm = wr + i * 16 + row0 + r;
                const int mg = m0 + mm;
                const float bi = (mg < 768) ? bias_lo[mg] : bias_hi[mg - 768];
                #pragma unroll
                for (int j = 0; j < 4; ++j) {
                    const int nl = wc + j * 16 + lr;
                    LDS[nl * 136 + mm] = (__bf16)(acc[i][j][r] + bi);
                }
            }
        }
        __syncthreads();
        __bf16* OutT = (__bf16*)Out;
        const int rown = tid >> 1;
        const int coff = (tid & 1) * 64;
        #pragma unroll
        for (int s = 0; s < 8; ++s) {
            const bf16x8 v = *(const bf16x8*)(LDS + rown * 136 + coff + s * 8);
            *(bf16x8*)(OutT + (size_t)(n0 + rown) * ldo + m0 + coff + s * 8) = v;
        }
    } else {
        #pragma unroll
        for (int i = 0; i < 4; ++i) {
            #pragma unroll
            for (int r = 0; r < 4; ++r) {
                const int mg = m0 + wr + i * 16 + row0 + r;
                const float bi = bias_lo[mg];
                #pragma unroll
                for (int j = 0; j < 4; ++j) {
                    const int nl = wc + j * 16 + lr;
                    const int b_ = n0 >> 11, lo = (n0 & 2047) + nl;
                    ((float*)Out)[((size_t)(b_ * KD + mg)) * L_SEQ + lo] = acc[i][j][r] + bi;
                }
            }
        }
    }
}

// merged K|V: A = [Wk;Wv] (1536x768). Grid 4608 = 12 m-tiles x 384 n-tiles,
// XCD-grouped (4608/8=576), m-fast so same-n-panel blocks share an XCD's L2.
__global__ __launch_bounds__(256, 2) void gemm_kv(
    const __bf16* __restrict__ Wkv, const float* __restrict__ bk, const float* __restrict__ bv,
    const __bf16* __restrict__ XT, __bf16* __restrict__ KVt)
{
    __shared__ __bf16 LDS[17408];
    const int bid = blockIdx.x;
    const int gidx = (bid & 7) * 576 + (bid >> 3);
    const int m0 = (gidx % 12) * 128;
    const int n0 = (gidx / 12) * 128;
    gemm_body<0>(Wkv, XT, bk, bv, KVt, KVLD, m0, n0, LDS);
}

template <int MODE, int NM>
__global__ __launch_bounds__(256, 2) void gemm_one(
    const __bf16* __restrict__ W, const float* __restrict__ bias,
    const __bf16* __restrict__ Bt, void* __restrict__ Out, int ldo)
{
    __shared__ __bf16 LDS[17408];
    const int bid = blockIdx.x;
    const int nwg8 = gridDim.x >> 3;
    const int gidx = (bid & 7) * nwg8 + (bid >> 3);
    const int m0 = (gidx % NM) * 128;
    const int n0 = (gidx / NM) * 128;
    gemm_body<MODE>(W, Bt, bias, bias, Out, ldo, m0, n0, LDS);
}

// ---------------- attention (transposed, 16B loads) ----------------
// Qt: [8192][768]; KVt: [49152][1536] (K at +0, V at +768); attT: [8192][768]
__global__ __launch_bounds__(256) void attn_kernel(
    const __bf16* __restrict__ Qt, const __bf16* __restrict__ KVt,
    __bf16* __restrict__ attT)
{
    const int bid = blockIdx.x;
    const int lt = bid & 63;
    const int h = bid >> 6;
    const int tid = threadIdx.x;
    const int wave = tid >> 6, lane = tid & 63;
    const int half = lane >> 5, ln = lane & 31;
    const int n = lt * 128 + wave * 32 + ln;
    const int l = n & (L_SEQ - 1);
    const int c0 = h * 64 + half * 32;

    float q[32];
    {
        const __bf16* qp = Qt + (size_t)n * KD + c0;
        #pragma unroll
        for (int s = 0; s < 4; ++s) {
            const bf16x8 v = *(const bf16x8*)(qp + s * 8);
            #pragma unroll
            for (int j = 0; j < 8; ++j) q[s * 8 + j] = (float)v[j];
        }
    }

    float sc[10];
    #pragma unroll
    for (int w = 0; w < 5; ++w) {
        const int lw = l + w - 2;
        float acc = 0.f;
        if ((unsigned)lw < L_SEQ) {
            const __bf16* kp = KVt + (size_t)(n + w - 2) * KVLD + c0;
            #pragma unroll
            for (int s = 0; s < 4; ++s) {
                const bf16x8 v = *(const bf16x8*)(kp + s * 8);
                #pragma unroll
                for (int j = 0; j < 8; ++j) acc += q[s * 8 + j] * (float)v[j];
            }
        }
        sc[w] = acc;
    }
    #pragma unroll
    for (int a = 0; a < 5; ++a) {
        const __bf16* kp = KVt + ((size_t)(a + 1) * NX + n) * KVLD + c0;
        float acc = 0.f;
        #pragma unroll
        for (int s = 0; s < 4; ++s) {
            const bf16x8 v = *(const bf16x8*)(kp + s * 8);
            #pragma unroll
            for (int j = 0; j < 8; ++j) acc += q[s * 8 + j] * (float)v[j];
        }
        sc[5 + a] = acc;
    }

    #pragma unroll
    for (int i = 0; i < 10; ++i) {
        sc[i] += __shfl_xor(sc[i], 32);
        sc[i] *= 0.125f;
    }

    float mx = sc[0];
    #pragma unroll
    for (int i = 1; i < 10; ++i) mx = fmaxf(mx, sc[i]);
    float e[10], sum = 0.f;
    #pragma unroll
    for (int i = 0; i < 10; ++i) { e[i] = __expf(sc[i] - mx); sum += e[i]; }
    const float inv = 1.f / sum;

    float o[32];
    #pragma unroll
    for (int i = 0; i < 32; ++i) o[i] = 0.f;

    #pragma unroll
    for (int w = 0; w < 5; ++w) {
        const int lw = l + w - 2;
        if ((unsigned)lw < L_SEQ) {
            const __bf16* vp = KVt + (size_t)(n + w - 2) * KVLD + 768 + c0;
            #pragma unroll
            for (int s = 0; s < 4; ++s) {
                const bf16x8 v = *(const bf16x8*)(vp + s * 8);
                #pragma unroll
                for (int j = 0; j < 8; ++j) o[s * 8 + j] += e[w] * (float)v[j];
            }
        }
    }
    #pragma unroll
    for (int a = 0; a < 5; ++a) {
        const __bf16* vp = KVt + ((size_t)(a + 1) * NX + n) * KVLD + 768 + c0;
        #pragma unroll
        for (int s = 0; s < 4; ++s) {
            const bf16x8 v = *(const bf16x8*)(vp + s * 8);
            #pragma unroll
            for (int j = 0; j < 8; ++j) o[s * 8 + j] += e[5 + a] * (float)v[j];
        }
    }

    __bf16* dst = attT + (size_t)n * KD + c0;
    #pragma unroll
    for (int s = 0; s < 4; ++s) {
        bf16x8 t;
        #pragma unroll
        for (int j = 0; j < 8; ++j) t[j] = (__bf16)(o[s * 8 + j] * inv);
        *(bf16x8*)(dst + s * 8) = t;
    }
}

extern "C" void kernel_launch(void* const* d_in, const int* in_sizes, int n_in,
                              void* d_out, int out_size, void* d_ws, size_t ws_size,
                              hipStream_t stream)
{
    const float* x  = (const float*)d_in[0];
    const float* ax = (const float*)d_in[1];
    const float* Wq = (const float*)d_in[2];
    const float* bq = (const float*)d_in[3];
    const float* Wk = (const float*)d_in[4];
    const float* bk = (const float*)d_in[5];
    const float* Wv = (const float*)d_in[6];
    const float* bv = (const float*)d_in[7];
    const float* Wo = (const float*)d_in[8];
    const float* bo = (const float*)d_in[9];
    float* out = (float*)d_out;

    __bf16* p = (__bf16*)d_ws;
    __bf16* Wq_bf = p; p += 589824;
    __bf16* Wkv_bf = p;                       // [Wk_bf; Wv_bf] contiguous
    __bf16* Wk_bf = p; p += 589824;
    __bf16* Wv_bf = p; p += 589824;
    __bf16* Wo_bf = p; p += 589824;
    __bf16* Qt    = p; p += (size_t)KD * NX;
    __bf16* KVt   = p; p += (size_t)KVLD * NALL;
    __bf16* XT    = p; p += (size_t)KD * NALL;
    __bf16* attT  = p;

    wconv_kernel<<<dim3(576, 4), dim3(256), 0, stream>>>(Wq, Wk, Wv, Wo, Wq_bf, Wk_bf, Wv_bf, Wo_bf);
    xconv_kernel<<<dim3(768, 12), dim3(256), 0, stream>>>(x, ax, XT);

    // KV merged: 12 m-tiles x 384 n-tiles = 4608 blocks (128x128 each)
    gemm_kv<<<dim3(4608), dim3(256), 0, stream>>>(Wkv_bf, bk, bv, XT, KVt);
    // Q: 6 m x 64 n = 384 blocks
    gemm_one<0, 6><<<dim3(384), dim3(256), 0, stream>>>(Wq_bf, bq, XT, Qt, KD);

    attn_kernel<<<dim3(64 * N_HEAD), dim3(256), 0, stream>>>(Qt, KVt, attT);

    // O: fp32 final out
    gemm_one<1, 6><<<dim3(384), dim3(256), 0, stream>>>(Wo_bf, bo, attT, out, 0);
}

// Round 13
// 251.273 us; speedup vs baseline: 2.7578x; 1.0884x over previous
//
#include <hip/hip_runtime.h>
#include <hip/hip_bf16.h>
#include <cstddef>
#include <cstdint>

typedef __attribute__((ext_vector_type(4))) __bf16 bf16x4;
typedef __attribute__((ext_vector_type(8))) __bf16 bf16x8;
typedef __attribute__((ext_vector_type(4))) float f32x4;

#define L_SEQ 2048
#define KD 768
#define N_HEAD 12
#define NB 4
#define NX 8192          // B*L
#define NALL 49152       // B*L*(1+5)
#define KVLD 1536        // merged K|V output row length

__device__ __forceinline__ void gload16(const __bf16* g, __bf16* l) {
    __builtin_amdgcn_global_load_lds(
        (const __attribute__((address_space(1))) void*)g,
        (__attribute__((address_space(3))) void*)l, 16, 0, 0);
}

// ---------------- weight fp32 -> bf16 ----------------
__global__ __launch_bounds__(256) void wconv_kernel(
    const float* __restrict__ W0, const float* __restrict__ W1,
    const float* __restrict__ W2, const float* __restrict__ W3,
    __bf16* __restrict__ O0, __bf16* __restrict__ O1,
    __bf16* __restrict__ O2, __bf16* __restrict__ O3)
{
    const float* src; __bf16* dst;
    switch (blockIdx.y) {
        case 0: src = W0; dst = O0; break;
        case 1: src = W1; dst = O1; break;
        case 2: src = W2; dst = O2; break;
        default: src = W3; dst = O3; break;
    }
    const int i = (blockIdx.x * 256 + threadIdx.x) * 4;
    const float4 v = *(const float4*)(src + i);
    bf16x4 t;
    t[0] = (__bf16)v.x; t[1] = (__bf16)v.y; t[2] = (__bf16)v.z; t[3] = (__bf16)v.w;
    *(bf16x4*)(dst + i) = t;
}

// ------------- convert+transpose into XT[n'(49152)][768] -------------
__global__ __launch_bounds__(256) void xconv_kernel(
    const float* __restrict__ x, const float* __restrict__ ax,
    __bf16* __restrict__ XT)
{
    __shared__ __bf16 S[64][72];
    const int t = threadIdx.x;
    const int ap = blockIdx.x >> 7;
    const int inner = blockIdx.x & 127;
    const int bb = inner >> 5;
    const int l0 = (inner & 31) * 64;
    const int d0 = blockIdx.y * 64;
    const int r = t >> 4;
    const int c4 = (t & 15) * 4;
    #pragma unroll
    for (int p = 0; p < 4; ++p) {
        const int d = d0 + r + p * 16;
        const float* src = (ap == 0)
            ? x + ((size_t)(bb * KD + d)) * L_SEQ
            : ax + (((size_t)(bb * KD + d)) * 5 + (ap - 1)) * L_SEQ;
        const float4 v = *(const float4*)(src + l0 + c4);
        S[c4 + 0][r + p * 16] = (__bf16)v.x;
        S[c4 + 1][r + p * 16] = (__bf16)v.y;
        S[c4 + 2][r + p * 16] = (__bf16)v.z;
        S[c4 + 3][r + p * 16] = (__bf16)v.w;
    }
    __syncthreads();
    #pragma unroll
    for (int p = 0; p < 4; ++p) {
        const int lr = r + p * 16;
        const bf16x4 v = *(const bf16x4*)&S[lr][c4];
        *(bf16x4*)(XT + ((size_t)ap * NX + bb * L_SEQ + l0 + lr) * KD + d0 + c4) = v;
    }
}

// ---------------- m97-structure 128x128 GEMM + 8-slot XOR swizzle (R11-proven) ----------------
// Out = A[M][768] * Bt[N][768]^T + bias. 256 thr = 4 waves (2x2 of 64x64),
// acc[4][4], single-buffered 32KB LDS, 2 barriers/step, gload_lds(16B).
// Involutive 8-slot XOR, both sides (rule #21): stage slot (lane&7)^(lane>>3),
// read slot (ks*4+kslc)^(lr&7) -> 2-way aliasing only (free, m136).
// R11 verified: conflicts 4.4e7 -> 1.2e6, 823 TF (structure ceiling).
template <int MODE>   // 0: bf16 OutT[n'][ldo], col m0; 1: fp32 out[(b*768+m)*2048+l]
__device__ __forceinline__ void gemm_body(
    const __bf16* __restrict__ A, const __bf16* __restrict__ Bt,
    const float* __restrict__ bias_lo, const float* __restrict__ bias_hi,
    void* __restrict__ Out, int ldo, int m0, int n0, __bf16* LDS)
{
    __bf16* As = LDS;
    __bf16* Bs = LDS + 8192;
    const int tid = threadIdx.x;
    const int lane = tid & 63, wave = tid >> 6;
    const int wr = (wave >> 1) * 64, wc = (wave & 1) * 64;
    const int lr = lane & 15;
    const int kslc = lane >> 4;               // 0..3
    const int srow = lane >> 3;               // 0..7
    const int skq = ((lane & 7) ^ srow) * 8;  // pre-swizzled global k-slot

    f32x4 acc[4][4];
    #pragma unroll
    for (int i = 0; i < 4; ++i)
        #pragma unroll
        for (int j = 0; j < 4; ++j)
            acc[i][j] = (f32x4){0.f, 0.f, 0.f, 0.f};

    for (int kt = 0; kt < KD; kt += 64) {
        __syncthreads();
        #pragma unroll
        for (int p = 0; p < 4; ++p) {
            const int rb = wave * 32 + p * 8;
            gload16(A  + (size_t)(m0 + rb + srow) * KD + kt + skq, As + rb * 64);
            gload16(Bt + (size_t)(n0 + rb + srow) * KD + kt + skq, Bs + rb * 64);
        }
        __syncthreads();
        #pragma unroll
        for (int ks = 0; ks < 2; ++ks) {
            const int ko = ((ks * 4 + kslc) ^ (lr & 7)) * 8;   // swizzled read slot
            bf16x8 a[4], b[4];
            #pragma unroll
            for (int f = 0; f < 4; ++f) a[f] = *(const bf16x8*)(As + (wr + f * 16 + lr) * 64 + ko);
            #pragma unroll
            for (int f = 0; f < 4; ++f) b[f] = *(const bf16x8*)(Bs + (wc + f * 16 + lr) * 64 + ko);
            #pragma unroll
            for (int i = 0; i < 4; ++i)
                #pragma unroll
                for (int j = 0; j < 4; ++j)
                    acc[i][j] = __builtin_amdgcn_mfma_f32_16x16x32_bf16(a[i], b[j], acc[i][j], 0, 0, 0);
        }
    }

    const int row0 = kslc * 4;   // C/D: col=lane&15 (n), row=(lane>>4)*4+reg (m)

    if (MODE == 0) {
        // transpose via LDS (reuse staging region), then coalesced 16B writes
        __syncthreads();
        #pragma unroll
        for (int i = 0; i < 4; ++i) {
            #pragma unroll
            for (int r = 0; r < 4; ++r) {
                const int mm = wr + i * 16 + row0 + r;
                const int mg = m0 + mm;
                const float bi = (mg < 768) ? bias_lo[mg] : bias_hi[mg - 768];
                #pragma unroll
                for (int j = 0; j < 4; ++j) {
                    const int nl = wc + j * 16 + lr;
                    LDS[nl * 136 + mm] = (__bf16)(acc[i][j][r] + bi);
                }
            }
        }
        __syncthreads();
        __bf16* OutT = (__bf16*)Out;
        const int rown = tid >> 1;
        const int coff = (tid & 1) * 64;
        #pragma unroll
        for (int s = 0; s < 8; ++s) {
            const bf16x8 v = *(const bf16x8*)(LDS + rown * 136 + coff + s * 8);
            *(bf16x8*)(OutT + (size_t)(n0 + rown) * ldo + m0 + coff + s * 8) = v;
        }
    } else {
        #pragma unroll
        for (int i = 0; i < 4; ++i) {
            #pragma unroll
            for (int r = 0; r < 4; ++r) {
                const int mg = m0 + wr + i * 16 + row0 + r;
                const float bi = bias_lo[mg];
                #pragma unroll
                for (int j = 0; j < 4; ++j) {
                    const int nl = wc + j * 16 + lr;
                    const int b_ = n0 >> 11, lo = (n0 & 2047) + nl;
                    ((float*)Out)[((size_t)(b_ * KD + mg)) * L_SEQ + lo] = acc[i][j][r] + bi;
                }
            }
        }
    }
}

// ---------------- merged Q|K|V projection, one launch ----------------
// Slot map (m-fast, XCD-chunked over 4992 = 8*624):
//   gidx < 1152: n-tile = gidx/18 (0..63, the x-token range), m-slot = gidx%18
//                (0..5 -> Q m-tile, 6..17 -> KV m-tile)
//   else:        n-tile = 64 + (gidx-1152)/12, m-slot = 6 + (gidx-1152)%12 (KV only)
// Q and KV slots of the same n-tile share the B-panel via the XCD's L2.
__global__ __launch_bounds__(256, 2) void gemm_qkv(
    const __bf16* __restrict__ Wq_bf, const __bf16* __restrict__ Wkv_bf,
    const float* __restrict__ bq, const float* __restrict__ bk, const float* __restrict__ bv,
    const __bf16* __restrict__ XT, __bf16* __restrict__ Qt, __bf16* __restrict__ KVt)
{
    __shared__ __bf16 LDS[17408];
    const int bid = blockIdx.x;
    const int gidx = (bid & 7) * 624 + (bid >> 3);
    int nt, mslot;
    if (gidx < 1152) { nt = gidx / 18; mslot = gidx % 18; }
    else { const int g2 = gidx - 1152; nt = 64 + g2 / 12; mslot = 6 + g2 % 12; }
    const int n0 = nt * 128;
    if (mslot < 6)
        gemm_body<0>(Wq_bf, XT, bq, bq, Qt, KD, mslot * 128, n0, LDS);
    else
        gemm_body<0>(Wkv_bf, XT, bk, bv, KVt, KVLD, (mslot - 6) * 128, n0, LDS);
}

// O projection: fp32 final out, 384 blocks
__global__ __launch_bounds__(256, 2) void gemm_o(
    const __bf16* __restrict__ W, const float* __restrict__ bias,
    const __bf16* __restrict__ Bt, float* __restrict__ Out)
{
    __shared__ __bf16 LDS[17408];
    const int bid = blockIdx.x;
    const int nwg8 = gridDim.x >> 3;
    const int gidx = (bid & 7) * nwg8 + (bid >> 3);
    const int m0 = (gidx % 6) * 128;
    const int n0 = (gidx / 6) * 128;
    gemm_body<1>(W, Bt, bias, bias, Out, 0, m0, n0, LDS);
}

// ---------------- attention (transposed, 16B loads, 4-way channel split) ----------------
// Qt: [8192][768]; KVt: [49152][1536] (K at +0, V at +768); attT: [8192][768]
// Thread = (n, head, 16-ch quarter): lane = q4*16 + ln; wave covers 16 n x 4 quarters.
// Score reduce: shfl_xor(16) + shfl_xor(32). Grid 1536 blocks -> 24 waves/CU TLP.
__global__ __launch_bounds__(256) void attn_kernel(
    const __bf16* __restrict__ Qt, const __bf16* __restrict__ KVt,
    __bf16* __restrict__ attT)
{
    const int bid = blockIdx.x;
    const int lt = bid & 127;            // 8192/64 = 128 n-tiles of 64
    const int h = bid >> 7;
    const int tid = threadIdx.x;
    const int wave = tid >> 6, lane = tid & 63;
    const int q4 = lane >> 4, ln = lane & 15;
    const int n = lt * 64 + wave * 16 + ln;
    const int l = n & (L_SEQ - 1);
    const int c0 = h * 64 + q4 * 16;

    float q[16];
    {
        const __bf16* qp = Qt + (size_t)n * KD + c0;
        #pragma unroll
        for (int s = 0; s < 2; ++s) {
            const bf16x8 v = *(const bf16x8*)(qp + s * 8);
            #pragma unroll
            for (int j = 0; j < 8; ++j) q[s * 8 + j] = (float)v[j];
        }
    }

    float sc[10];
    #pragma unroll
    for (int w = 0; w < 5; ++w) {
        const int lw = l + w - 2;
        float acc = 0.f;
        if ((unsigned)lw < L_SEQ) {
            const __bf16* kp = KVt + (size_t)(n + w - 2) * KVLD + c0;
            #pragma unroll
            for (int s = 0; s < 2; ++s) {
                const bf16x8 v = *(const bf16x8*)(kp + s * 8);
                #pragma unroll
                for (int j = 0; j < 8; ++j) acc += q[s * 8 + j] * (float)v[j];
            }
        }
        sc[w] = acc;
    }
    #pragma unroll
    for (int a = 0; a < 5; ++a) {
        const __bf16* kp = KVt + ((size_t)(a + 1) * NX + n) * KVLD + c0;
        float acc = 0.f;
        #pragma unroll
        for (int s = 0; s < 2; ++s) {
            const bf16x8 v = *(const bf16x8*)(kp + s * 8);
            #pragma unroll
            for (int j = 0; j < 8; ++j) acc += q[s * 8 + j] * (float)v[j];
        }
        sc[5 + a] = acc;
    }

    #pragma unroll
    for (int i = 0; i < 10; ++i) {
        sc[i] += __shfl_xor(sc[i], 16);
        sc[i] += __shfl_xor(sc[i], 32);
        sc[i] *= 0.125f;
    }

    float mx = sc[0];
    #pragma unroll
    for (int i = 1; i < 10; ++i) mx = fmaxf(mx, sc[i]);
    float e[10], sum = 0.f;
    #pragma unroll
    for (int i = 0; i < 10; ++i) { e[i] = __expf(sc[i] - mx); sum += e[i]; }
    const float inv = 1.f / sum;

    float o[16];
    #pragma unroll
    for (int i = 0; i < 16; ++i) o[i] = 0.f;

    #pragma unroll
    for (int w = 0; w < 5; ++w) {
        const int lw = l + w - 2;
        if ((unsigned)lw < L_SEQ) {
            const __bf16* vp = KVt + (size_t)(n + w - 2) * KVLD + 768 + c0;
            #pragma unroll
            for (int s = 0; s < 2; ++s) {
                const bf16x8 v = *(const bf16x8*)(vp + s * 8);
                #pragma unroll
                for (int j = 0; j < 8; ++j) o[s * 8 + j] += e[w] * (float)v[j];
            }
        }
    }
    #pragma unroll
    for (int a = 0; a < 5; ++a) {
        const __bf16* vp = KVt + ((size_t)(a + 1) * NX + n) * KVLD + 768 + c0;
        #pragma unroll
        for (int s = 0; s < 2; ++s) {
            const bf16x8 v = *(const bf16x8*)(vp + s * 8);
            #pragma unroll
            for (int j = 0; j < 8; ++j) o[s * 8 + j] += e[5 + a] * (float)v[j];
        }
    }

    __bf16* dst = attT + (size_t)n * KD + c0;
    #pragma unroll
    for (int s = 0; s < 2; ++s) {
        bf16x8 t;
        #pragma unroll
        for (int j = 0; j < 8; ++j) t[j] = (__bf16)(o[s * 8 + j] * inv);
        *(bf16x8*)(dst + s * 8) = t;
    }
}

extern "C" void kernel_launch(void* const* d_in, const int* in_sizes, int n_in,
                              void* d_out, int out_size, void* d_ws, size_t ws_size,
                              hipStream_t stream)
{
    const float* x  = (const float*)d_in[0];
    const float* ax = (const float*)d_in[1];
    const float* Wq = (const float*)d_in[2];
    const float* bq = (const float*)d_in[3];
    const float* Wk = (const float*)d_in[4];
    const float* bk = (const float*)d_in[5];
    const float* Wv = (const float*)d_in[6];
    const float* bv = (const float*)d_in[7];
    const float* Wo = (const float*)d_in[8];
    const float* bo = (const float*)d_in[9];
    float* out = (float*)d_out;

    __bf16* p = (__bf16*)d_ws;
    __bf16* Wq_bf = p; p += 589824;
    __bf16* Wkv_bf = p;                       // [Wk_bf; Wv_bf] contiguous
    __bf16* Wk_bf = p; p += 589824;
    __bf16* Wv_bf = p; p += 589824;
    __bf16* Wo_bf = p; p += 589824;
    __bf16* Qt    = p; p += (size_t)KD * NX;
    __bf16* KVt   = p; p += (size_t)KVLD * NALL;
    __bf16* XT    = p; p += (size_t)KD * NALL;
    __bf16* attT  = p;

    wconv_kernel<<<dim3(576, 4), dim3(256), 0, stream>>>(Wq, Wk, Wv, Wo, Wq_bf, Wk_bf, Wv_bf, Wo_bf);
    xconv_kernel<<<dim3(768, 12), dim3(256), 0, stream>>>(x, ax, XT);

    // merged Q|K|V: 64 n-tiles x 18 slots + 320 n-tiles x 12 slots = 4992 blocks
    gemm_qkv<<<dim3(4992), dim3(256), 0, stream>>>(Wq_bf, Wkv_bf, bq, bk, bv, XT, Qt, KVt);

    attn_kernel<<<dim3(128 * N_HEAD), dim3(256), 0, stream>>>(Qt, KVt, attT);

    // O: fp32 final out, 6 m x 64 n = 384 blocks
    gemm_o<<<dim3(384), dim3(256), 0, stream>>>(Wo_bf, bo, attT, out);
}

// Round 14
// 245.592 us; speedup vs baseline: 2.8216x; 1.0231x over previous
//
#include <hip/hip_runtime.h>
#include <hip/hip_bf16.h>
#include <cstddef>
#include <cstdint>

typedef __attribute__((ext_vector_type(4))) __bf16 bf16x4;
typedef __attribute__((ext_vector_type(8))) __bf16 bf16x8;
typedef __attribute__((ext_vector_type(4))) float f32x4;

#define L_SEQ 2048
#define KD 768
#define N_HEAD 12
#define NB 4
#define NX 8192          // B*L
#define NALL 49152       // B*L*(1+5)
#define KVLD 1536        // merged K|V output row length

__device__ __forceinline__ void gload16(const __bf16* g, __bf16* l) {
    __builtin_amdgcn_global_load_lds(
        (const __attribute__((address_space(1))) void*)g,
        (__attribute__((address_space(3))) void*)l, 16, 0, 0);
}

// ------------- convert+transpose into XT[n'(49152)][768]  (+ weight conv on y==12) -------------
__global__ __launch_bounds__(256) void xconv_kernel(
    const float* __restrict__ x, const float* __restrict__ ax,
    __bf16* __restrict__ XT,
    const float* __restrict__ W0, const float* __restrict__ W1,
    const float* __restrict__ W2, const float* __restrict__ W3,
    __bf16* __restrict__ O0, __bf16* __restrict__ O1,
    __bf16* __restrict__ O2, __bf16* __restrict__ O3)
{
    const int t = threadIdx.x;
    if (blockIdx.y == 12) {
        // weight fp32->bf16: 768 blocks x 3072 elems (4 x 589824 total)
        const int bx = blockIdx.x;
        const float* src; __bf16* dst;
        switch (bx / 192) {
            case 0: src = W0; dst = O0; break;
            case 1: src = W1; dst = O1; break;
            case 2: src = W2; dst = O2; break;
            default: src = W3; dst = O3; break;
        }
        const int i0 = (bx % 192) * 3072 + t * 12;
        #pragma unroll
        for (int s = 0; s < 3; ++s) {
            const float4 v = *(const float4*)(src + i0 + s * 4);
            bf16x4 w;
            w[0] = (__bf16)v.x; w[1] = (__bf16)v.y; w[2] = (__bf16)v.z; w[3] = (__bf16)v.w;
            *(bf16x4*)(dst + i0 + s * 4) = w;
        }
        return;
    }
    __shared__ __bf16 S[64][72];
    const int ap = blockIdx.x >> 7;
    const int inner = blockIdx.x & 127;
    const int bb = inner >> 5;
    const int l0 = (inner & 31) * 64;
    const int d0 = blockIdx.y * 64;
    const int r = t >> 4;
    const int c4 = (t & 15) * 4;
    #pragma unroll
    for (int p = 0; p < 4; ++p) {
        const int d = d0 + r + p * 16;
        const float* src = (ap == 0)
            ? x + ((size_t)(bb * KD + d)) * L_SEQ
            : ax + (((size_t)(bb * KD + d)) * 5 + (ap - 1)) * L_SEQ;
        const float4 v = *(const float4*)(src + l0 + c4);
        S[c4 + 0][r + p * 16] = (__bf16)v.x;
        S[c4 + 1][r + p * 16] = (__bf16)v.y;
        S[c4 + 2][r + p * 16] = (__bf16)v.z;
        S[c4 + 3][r + p * 16] = (__bf16)v.w;
    }
    __syncthreads();
    #pragma unroll
    for (int p = 0; p < 4; ++p) {
        const int lr = r + p * 16;
        const bf16x4 v = *(const bf16x4*)&S[lr][c4];
        *(bf16x4*)(XT + ((size_t)ap * NX + bb * L_SEQ + l0 + lr) * KD + d0 + c4) = v;
    }
}

// ---------------- m97-structure 128x128 GEMM + 8-slot XOR swizzle (R11-proven) ----------------
// Out = A[M][768] * Bt[N][768]^T + bias. 256 thr = 4 waves (2x2 of 64x64),
// acc[4][4], single-buffered 32KB LDS, 2 barriers/step, gload_lds(16B).
// Involutive 8-slot XOR, both sides (rule #21): stage slot (lane&7)^(lane>>3),
// read slot (ks*4+kslc)^(lr&7) -> 2-way aliasing only (free, m136).
// R11/R12 verified: conflicts 4.4e7 -> 1.2e6, ~820 TF (structure ceiling @K=768).
template <int MODE>   // 0: bf16 OutT[n'][ldo], col m0; 1: fp32 out[(b*768+m)*2048+l]
__device__ __forceinline__ void gemm_body(
    const __bf16* __restrict__ A, const __bf16* __restrict__ Bt,
    const float* __restrict__ bias_lo, const float* __restrict__ bias_hi,
    void* __restrict__ Out, int ldo, int m0, int n0, __bf16* LDS)
{
    __bf16* As = LDS;
    __bf16* Bs = LDS + 8192;
    const int tid = threadIdx.x;
    const int lane = tid & 63, wave = tid >> 6;
    const int wr = (wave >> 1) * 64, wc = (wave & 1) * 64;
    const int lr = lane & 15;
    const int kslc = lane >> 4;               // 0..3
    const int srow = lane >> 3;               // 0..7
    const int skq = ((lane & 7) ^ srow) * 8;  // pre-swizzled global k-slot

    f32x4 acc[4][4];
    #pragma unroll
    for (int i = 0; i < 4; ++i)
        #pragma unroll
        for (int j = 0; j < 4; ++j)
            acc[i][j] = (f32x4){0.f, 0.f, 0.f, 0.f};

    for (int kt = 0; kt < KD; kt += 64) {
        __syncthreads();
        #pragma unroll
        for (int p = 0; p < 4; ++p) {
            const int rb = wave * 32 + p * 8;
            gload16(A  + (size_t)(m0 + rb + srow) * KD + kt + skq, As + rb * 64);
            gload16(Bt + (size_t)(n0 + rb + srow) * KD + kt + skq, Bs + rb * 64);
        }
        __syncthreads();
        #pragma unroll
        for (int ks = 0; ks < 2; ++ks) {
            const int ko = ((ks * 4 + kslc) ^ (lr & 7)) * 8;   // swizzled read slot
            bf16x8 a[4], b[4];
            #pragma unroll
            for (int f = 0; f < 4; ++f) a[f] = *(const bf16x8*)(As + (wr + f * 16 + lr) * 64 + ko);
            #pragma unroll
            for (int f = 0; f < 4; ++f) b[f] = *(const bf16x8*)(Bs + (wc + f * 16 + lr) * 64 + ko);
            #pragma unroll
            for (int i = 0; i < 4; ++i)
                #pragma unroll
                for (int j = 0; j < 4; ++j)
                    acc[i][j] = __builtin_amdgcn_mfma_f32_16x16x32_bf16(a[i], b[j], acc[i][j], 0, 0, 0);
        }
    }

    const int row0 = kslc * 4;   // C/D: col=lane&15 (n), row=(lane>>4)*4+reg (m)

    if (MODE == 0) {
        __syncthreads();
        #pragma unroll
        for (int i = 0; i < 4; ++i) {
            #pragma unroll
            for (int r = 0; r < 4; ++r) {
                const int mm = wr + i * 16 + row0 + r;
                const int mg = m0 + mm;
                const float bi = (mg < 768) ? bias_lo[mg] : bias_hi[mg - 768];
                #pragma unroll
                for (int j = 0; j < 4; ++j) {
                    const int nl = wc + j * 16 + lr;
                    LDS[nl * 136 + mm] = (__bf16)(acc[i][j][r] + bi);
                }
            }
        }
        __syncthreads();
        __bf16* OutT = (__bf16*)Out;
        const int rown = tid >> 1;
        const int coff = (tid & 1) * 64;
        #pragma unroll
        for (int s = 0; s < 8; ++s) {
            const bf16x8 v = *(const bf16x8*)(LDS + rown * 136 + coff + s * 8);
            *(bf16x8*)(OutT + (size_t)(n0 + rown) * ldo + m0 + coff + s * 8) = v;
        }
    } else {
        #pragma unroll
        for (int i = 0; i < 4; ++i) {
            #pragma unroll
            for (int r = 0; r < 4; ++r) {
                const int mg = m0 + wr + i * 16 + row0 + r;
                const float bi = bias_lo[mg];
                #pragma unroll
                for (int j = 0; j < 4; ++j) {
                    const int nl = wc + j * 16 + lr;
                    const int b_ = n0 >> 11, lo = (n0 & 2047) + nl;
                    ((float*)Out)[((size_t)(b_ * KD + mg)) * L_SEQ + lo] = acc[i][j][r] + bi;
                }
            }
        }
    }
}

// ---------------- merged Q|K|V projection, one launch (R12-proven) ----------------
__global__ __launch_bounds__(256, 2) void gemm_qkv(
    const __bf16* __restrict__ Wq_bf, const __bf16* __restrict__ Wkv_bf,
    const float* __restrict__ bq, const float* __restrict__ bk, const float* __restrict__ bv,
    const __bf16* __restrict__ XT, __bf16* __restrict__ Qt, __bf16* __restrict__ KVt)
{
    __shared__ __bf16 LDS[17408];
    const int bid = blockIdx.x;
    const int gidx = (bid & 7) * 624 + (bid >> 3);
    int nt, mslot;
    if (gidx < 1152) { nt = gidx / 18; mslot = gidx % 18; }
    else { const int g2 = gidx - 1152; nt = 64 + g2 / 12; mslot = 6 + g2 % 12; }
    const int n0 = nt * 128;
    if (mslot < 6)
        gemm_body<0>(Wq_bf, XT, bq, bq, Qt, KD, mslot * 128, n0, LDS);
    else
        gemm_body<0>(Wkv_bf, XT, bk, bv, KVt, KVLD, (mslot - 6) * 128, n0, LDS);
}

// O projection: fp32 final out, 384 blocks
__global__ __launch_bounds__(256, 2) void gemm_o(
    const __bf16* __restrict__ W, const float* __restrict__ bias,
    const __bf16* __restrict__ Bt, float* __restrict__ Out)
{
    __shared__ __bf16 LDS[17408];
    const int bid = blockIdx.x;
    const int nwg8 = gridDim.x >> 3;
    const int gidx = (bid & 7) * nwg8 + (bid >> 3);
    const int m0 = (gidx % 6) * 128;
    const int n0 = (gidx / 6) * 128;
    gemm_body<1>(W, Bt, bias, bias, Out, 0, m0, n0, LDS);
}

// ---------------- attention (transposed, 8-way channel split, XCD-grouped) ----------------
// Qt: [8192][768]; KVt: [49152][1536] (K at +0, V at +768); attT: [8192][768]
// Thread = (n, head, 8-ch eighth): lane = e8*8 + ln; wave covers 8 n x 8 eighths.
// Reduce: shfl_xor(8)+(16)+(32). Grid 3072 = 8 XCD x 384; all 12 heads of an
// n-tile colocate on one XCD -> shared K/V rows hit that XCD's L2.
__global__ __launch_bounds__(256) void attn_kernel(
    const __bf16* __restrict__ Qt, const __bf16* __restrict__ KVt,
    __bf16* __restrict__ attT)
{
    const int bid = blockIdx.x;
    const int gidx = (bid & 7) * 384 + (bid >> 3);
    const int h = gidx % N_HEAD;
    const int lt = gidx / N_HEAD;        // 0..255, 32 n each
    const int tid = threadIdx.x;
    const int wave = tid >> 6, lane = tid & 63;
    const int e8 = lane >> 3, ln = lane & 7;
    const int n = lt * 32 + wave * 8 + ln;
    const int l = n & (L_SEQ - 1);
    const int c0 = h * 64 + e8 * 8;

    float q[8];
    {
        const bf16x8 v = *(const bf16x8*)(Qt + (size_t)n * KD + c0);
        #pragma unroll
        for (int j = 0; j < 8; ++j) q[j] = (float)v[j];
    }

    float sc[10];
    #pragma unroll
    for (int w = 0; w < 5; ++w) {
        const int lw = l + w - 2;
        float acc = 0.f;
        if ((unsigned)lw < L_SEQ) {
            const bf16x8 v = *(const bf16x8*)(KVt + (size_t)(n + w - 2) * KVLD + c0);
            #pragma unroll
            for (int j = 0; j < 8; ++j) acc += q[j] * (float)v[j];
        }
        sc[w] = acc;
    }
    #pragma unroll
    for (int a = 0; a < 5; ++a) {
        const bf16x8 v = *(const bf16x8*)(KVt + ((size_t)(a + 1) * NX + n) * KVLD + c0);
        float acc = 0.f;
        #pragma unroll
        for (int j = 0; j < 8; ++j) acc += q[j] * (float)v[j];
        sc[5 + a] = acc;
    }

    #pragma unroll
    for (int i = 0; i < 10; ++i) {
        sc[i] += __shfl_xor(sc[i], 8);
        sc[i] += __shfl_xor(sc[i], 16);
        sc[i] += __shfl_xor(sc[i], 32);
        sc[i] *= 0.125f;                   // 1/sqrt(64)
    }

    float mx = sc[0];
    #pragma unroll
    for (int i = 1; i < 10; ++i) mx = fmaxf(mx, sc[i]);
    float e[10], sum = 0.f;
    #pragma unroll
    for (int i = 0; i < 10; ++i) { e[i] = __expf(sc[i] - mx); sum += e[i]; }
    const float inv = 1.f / sum;

    float o[8];
    #pragma unroll
    for (int i = 0; i < 8; ++i) o[i] = 0.f;

    #pragma unroll
    for (int w = 0; w < 5; ++w) {
        const int lw = l + w - 2;
        if ((unsigned)lw < L_SEQ) {
            const bf16x8 v = *(const bf16x8*)(KVt + (size_t)(n + w - 2) * KVLD + 768 + c0);
            #pragma unroll
            for (int j = 0; j < 8; ++j) o[j] += e[w] * (float)v[j];
        }
    }
    #pragma unroll
    for (int a = 0; a < 5; ++a) {
        const bf16x8 v = *(const bf16x8*)(KVt + ((size_t)(a + 1) * NX + n) * KVLD + 768 + c0);
        #pragma unroll
        for (int j = 0; j < 8; ++j) o[j] += e[5 + a] * (float)v[j];
    }

    bf16x8 t;
    #pragma unroll
    for (int j = 0; j < 8; ++j) t[j] = (__bf16)(o[j] * inv);
    *(bf16x8*)(attT + (size_t)n * KD + c0) = t;
}

extern "C" void kernel_launch(void* const* d_in, const int* in_sizes, int n_in,
                              void* d_out, int out_size, void* d_ws, size_t ws_size,
                              hipStream_t stream)
{
    const float* x  = (const float*)d_in[0];
    const float* ax = (const float*)d_in[1];
    const float* Wq = (const float*)d_in[2];
    const float* bq = (const float*)d_in[3];
    const float* Wk = (const float*)d_in[4];
    const float* bk = (const float*)d_in[5];
    const float* Wv = (const float*)d_in[6];
    const float* bv = (const float*)d_in[7];
    const float* Wo = (const float*)d_in[8];
    const float* bo = (const float*)d_in[9];
    float* out = (float*)d_out;

    __bf16* p = (__bf16*)d_ws;
    __bf16* Wq_bf = p; p += 589824;
    __bf16* Wkv_bf = p;                       // [Wk_bf; Wv_bf] contiguous
    __bf16* Wk_bf = p; p += 589824;
    __bf16* Wv_bf = p; p += 589824;
    __bf16* Wo_bf = p; p += 589824;
    __bf16* Qt    = p; p += (size_t)KD * NX;
    __bf16* KVt   = p; p += (size_t)KVLD * NALL;
    __bf16* XT    = p; p += (size_t)KD * NALL;
    __bf16* attT  = p;

    // xconv (y 0..11) + weight conversion (y == 12) in one launch
    xconv_kernel<<<dim3(768, 13), dim3(256), 0, stream>>>(
        x, ax, XT, Wq, Wk, Wv, Wo, Wq_bf, Wk_bf, Wv_bf, Wo_bf);

    // merged Q|K|V: 64 n-tiles x 18 slots + 320 n-tiles x 12 slots = 4992 blocks
    gemm_qkv<<<dim3(4992), dim3(256), 0, stream>>>(Wq_bf, Wkv_bf, bq, bk, bv, XT, Qt, KVt);

    attn_kernel<<<dim3(3072), dim3(256), 0, stream>>>(Qt, KVt, attT);

    // O: fp32 final out, 6 m x 64 n = 384 blocks
    gemm_o<<<dim3(384), dim3(256), 0, stream>>>(Wo_bf, bo, attT, out);
}

// Round 15
// 230.223 us; speedup vs baseline: 3.0100x; 1.0668x over previous
//
#include <hip/hip_runtime.h>
#include <hip/hip_bf16.h>
#include <cstddef>
#include <cstdint>

typedef __attribute__((ext_vector_type(4))) __bf16 bf16x4;
typedef __attribute__((ext_vector_type(8))) __bf16 bf16x8;
typedef __attribute__((ext_vector_type(4))) float f32x4;

#define L_SEQ 2048
#define KD 768
#define N_HEAD 12
#define NB 4
#define NX 8192          // B*L
#define NALL 49152       // B*L*(1+5)
#define KVLD 1536        // merged K|V output row length

__device__ __forceinline__ void gload16(const __bf16* g, __bf16* l) {
    __builtin_amdgcn_global_load_lds(
        (const __attribute__((address_space(1))) void*)g,
        (__attribute__((address_space(3))) void*)l, 16, 0, 0);
}

// ------------- convert+transpose into XT[n'(49152)][768]  (+ weight conv on y==12) -------------
__global__ __launch_bounds__(256) void xconv_kernel(
    const float* __restrict__ x, const float* __restrict__ ax,
    __bf16* __restrict__ XT,
    const float* __restrict__ W0, const float* __restrict__ W1,
    const float* __restrict__ W2, const float* __restrict__ W3,
    __bf16* __restrict__ O0, __bf16* __restrict__ O1,
    __bf16* __restrict__ O2, __bf16* __restrict__ O3)
{
    const int t = threadIdx.x;
    if (blockIdx.y == 12) {
        const int bx = blockIdx.x;
        const float* src; __bf16* dst;
        switch (bx / 192) {
            case 0: src = W0; dst = O0; break;
            case 1: src = W1; dst = O1; break;
            case 2: src = W2; dst = O2; break;
            default: src = W3; dst = O3; break;
        }
        const int i0 = (bx % 192) * 3072 + t * 12;
        #pragma unroll
        for (int s = 0; s < 3; ++s) {
            const float4 v = *(const float4*)(src + i0 + s * 4);
            bf16x4 w;
            w[0] = (__bf16)v.x; w[1] = (__bf16)v.y; w[2] = (__bf16)v.z; w[3] = (__bf16)v.w;
            *(bf16x4*)(dst + i0 + s * 4) = w;
        }
        return;
    }
    __shared__ __bf16 S[64][72];
    const int ap = blockIdx.x >> 7;
    const int inner = blockIdx.x & 127;
    const int bb = inner >> 5;
    const int l0 = (inner & 31) * 64;
    const int d0 = blockIdx.y * 64;
    const int r = t >> 4;
    const int c4 = (t & 15) * 4;
    #pragma unroll
    for (int p = 0; p < 4; ++p) {
        const int d = d0 + r + p * 16;
        const float* src = (ap == 0)
            ? x + ((size_t)(bb * KD + d)) * L_SEQ
            : ax + (((size_t)(bb * KD + d)) * 5 + (ap - 1)) * L_SEQ;
        const float4 v = *(const float4*)(src + l0 + c4);
        S[c4 + 0][r + p * 16] = (__bf16)v.x;
        S[c4 + 1][r + p * 16] = (__bf16)v.y;
        S[c4 + 2][r + p * 16] = (__bf16)v.z;
        S[c4 + 3][r + p * 16] = (__bf16)v.w;
    }
    __syncthreads();
    #pragma unroll
    for (int p = 0; p < 4; ++p) {
        const int lr = r + p * 16;
        const bf16x4 v = *(const bf16x4*)&S[lr][c4];
        *(bf16x4*)(XT + ((size_t)ap * NX + bb * L_SEQ + l0 + lr) * KD + d0 + c4) = v;
    }
}

// ---------------- m97-structure 128x128 GEMM, 32KB LDS, 4 blocks/CU ----------------
// Out = A[M][768] * Bt[N][768]^T + bias. 256 thr = 4 waves (2x2 of 64x64),
// acc[4][4], single-buffered 32KB LDS, 2 barriers/step, gload_lds(16B).
// 8-slot XOR swizzle both sides (R11-proven: conflicts 4.4e7 -> 1.2e6).
// R14: epilogue uses per-wave 16x72 private LDS chunks inside the staging
// region (no 128x136 buffer) -> LDS_Block_Size 34816 -> 32768, and
// __launch_bounds__(256,4) -> 4 blocks/CU of independent barrier domains.
template <int MODE>   // 0: bf16 OutT[n'][ldo], col m0; 1: fp32 out[(b*768+m)*2048+l]
__device__ __forceinline__ void gemm_body(
    const __bf16* __restrict__ A, const __bf16* __restrict__ Bt,
    const float* __restrict__ bias_lo, const float* __restrict__ bias_hi,
    void* __restrict__ Out, int ldo, int m0, int n0, __bf16* LDS)
{
    __bf16* As = LDS;
    __bf16* Bs = LDS + 8192;
    const int tid = threadIdx.x;
    const int lane = tid & 63, wave = tid >> 6;
    const int wr = (wave >> 1) * 64, wc = (wave & 1) * 64;
    const int lr = lane & 15;
    const int kslc = lane >> 4;               // 0..3
    const int srow = lane >> 3;               // 0..7
    const int skq = ((lane & 7) ^ srow) * 8;  // pre-swizzled global k-slot

    f32x4 acc[4][4];
    #pragma unroll
    for (int i = 0; i < 4; ++i)
        #pragma unroll
        for (int j = 0; j < 4; ++j)
            acc[i][j] = (f32x4){0.f, 0.f, 0.f, 0.f};

    for (int kt = 0; kt < KD; kt += 64) {
        __syncthreads();
        #pragma unroll
        for (int p = 0; p < 4; ++p) {
            const int rb = wave * 32 + p * 8;
            gload16(A  + (size_t)(m0 + rb + srow) * KD + kt + skq, As + rb * 64);
            gload16(Bt + (size_t)(n0 + rb + srow) * KD + kt + skq, Bs + rb * 64);
        }
        __syncthreads();
        #pragma unroll
        for (int ks = 0; ks < 2; ++ks) {
            const int ko = ((ks * 4 + kslc) ^ (lr & 7)) * 8;   // swizzled read slot
            bf16x8 a[4], b[4];
            #pragma unroll
            for (int f = 0; f < 4; ++f) a[f] = *(const bf16x8*)(As + (wr + f * 16 + lr) * 64 + ko);
            #pragma unroll
            for (int f = 0; f < 4; ++f) b[f] = *(const bf16x8*)(Bs + (wc + f * 16 + lr) * 64 + ko);
            #pragma unroll
            for (int i = 0; i < 4; ++i)
                #pragma unroll
                for (int j = 0; j < 4; ++j)
                    acc[i][j] = __builtin_amdgcn_mfma_f32_16x16x32_bf16(a[i], b[j], acc[i][j], 0, 0, 0);
        }
    }

    const int row0 = kslc * 4;   // C/D: col=lane&15 (n), row=(lane>>4)*4+reg (m)

    if (MODE == 0) {
        // per-wave private transpose chunk (16 n-rows x 72), no cross-wave barriers
        __syncthreads();                      // WAR vs other waves' last staging reads
        __bf16* T = LDS + wave * 1152;
        const int rr = lane >> 2, seg = lane & 3;
        #pragma unroll
        for (int j = 0; j < 4; ++j) {
            #pragma unroll
            for (int i = 0; i < 4; ++i) {
                bf16x4 v;
                #pragma unroll
                for (int r = 0; r < 4; ++r) {
                    const int mg = m0 + wr + i * 16 + row0 + r;
                    const float bi = (mg < 768) ? bias_lo[mg] : bias_hi[mg - 768];
                    v[r] = (__bf16)(acc[i][j][r] + bi);
                }
                *(bf16x4*)(T + lr * 72 + i * 16 + row0) = v;
            }
            asm volatile("s_waitcnt lgkmcnt(0)" ::: "memory");   // intra-wave RAW
            __bf16* dst = (__bf16*)Out + (size_t)(n0 + wc + j * 16 + rr) * ldo
                          + m0 + wr + seg * 16;
            const __bf16* src = T + rr * 72 + seg * 16;
            *(bf16x8*)dst = *(const bf16x8*)src;
            *(bf16x8*)(dst + 8) = *(const bf16x8*)(src + 8);
            asm volatile("s_waitcnt lgkmcnt(0)" ::: "memory");   // WAR before next j
        }
    } else {
        #pragma unroll
        for (int i = 0; i < 4; ++i) {
            #pragma unroll
            for (int r = 0; r < 4; ++r) {
                const int mg = m0 + wr + i * 16 + row0 + r;
                const float bi = bias_lo[mg];
                #pragma unroll
                for (int j = 0; j < 4; ++j) {
                    const int nl = wc + j * 16 + lr;
                    const int b_ = n0 >> 11, lo = (n0 & 2047) + nl;
                    ((float*)Out)[((size_t)(b_ * KD + mg)) * L_SEQ + lo] = acc[i][j][r] + bi;
                }
            }
        }
    }
}

// ---------------- merged Q|K|V projection, one launch ----------------
__global__ __launch_bounds__(256, 4) void gemm_qkv(
    const __bf16* __restrict__ Wq_bf, const __bf16* __restrict__ Wkv_bf,
    const float* __restrict__ bq, const float* __restrict__ bk, const float* __restrict__ bv,
    const __bf16* __restrict__ XT, __bf16* __restrict__ Qt, __bf16* __restrict__ KVt)
{
    __shared__ __bf16 LDS[16384];
    const int bid = blockIdx.x;
    const int gidx = (bid & 7) * 624 + (bid >> 3);
    int nt, mslot;
    if (gidx < 1152) { nt = gidx / 18; mslot = gidx % 18; }
    else { const int g2 = gidx - 1152; nt = 64 + g2 / 12; mslot = 6 + g2 % 12; }
    const int n0 = nt * 128;
    if (mslot < 6)
        gemm_body<0>(Wq_bf, XT, bq, bq, Qt, KD, mslot * 128, n0, LDS);
    else
        gemm_body<0>(Wkv_bf, XT, bk, bv, KVt, KVLD, (mslot - 6) * 128, n0, LDS);
}

// O projection: fp32 final out, 384 blocks
__global__ __launch_bounds__(256, 4) void gemm_o(
    const __bf16* __restrict__ W, const float* __restrict__ bias,
    const __bf16* __restrict__ Bt, float* __restrict__ Out)
{
    __shared__ __bf16 LDS[16384];
    const int bid = blockIdx.x;
    const int nwg8 = gridDim.x >> 3;
    const int gidx = (bid & 7) * nwg8 + (bid >> 3);
    const int m0 = (gidx % 6) * 128;
    const int n0 = (gidx / 6) * 128;
    gemm_body<1>(W, Bt, bias, bias, Out, 0, m0, n0, LDS);
}

// ---------------- attention (transposed, 8-way channel split, XCD-grouped) ----------------
__global__ __launch_bounds__(256) void attn_kernel(
    const __bf16* __restrict__ Qt, const __bf16* __restrict__ KVt,
    __bf16* __restrict__ attT)
{
    const int bid = blockIdx.x;
    const int gidx = (bid & 7) * 384 + (bid >> 3);
    const int h = gidx % N_HEAD;
    const int lt = gidx / N_HEAD;        // 0..255, 32 n each
    const int tid = threadIdx.x;
    const int wave = tid >> 6, lane = tid & 63;
    const int e8 = lane >> 3, ln = lane & 7;
    const int n = lt * 32 + wave * 8 + ln;
    const int l = n & (L_SEQ - 1);
    const int c0 = h * 64 + e8 * 8;

    float q[8];
    {
        const bf16x8 v = *(const bf16x8*)(Qt + (size_t)n * KD + c0);
        #pragma unroll
        for (int j = 0; j < 8; ++j) q[j] = (float)v[j];
    }

    float sc[10];
    #pragma unroll
    for (int w = 0; w < 5; ++w) {
        const int lw = l + w - 2;
        float acc = 0.f;
        if ((unsigned)lw < L_SEQ) {
            const bf16x8 v = *(const bf16x8*)(KVt + (size_t)(n + w - 2) * KVLD + c0);
            #pragma unroll
            for (int j = 0; j < 8; ++j) acc += q[j] * (float)v[j];
        }
        sc[w] = acc;
    }
    #pragma unroll
    for (int a = 0; a < 5; ++a) {
        const bf16x8 v = *(const bf16x8*)(KVt + ((size_t)(a + 1) * NX + n) * KVLD + c0);
        float acc = 0.f;
        #pragma unroll
        for (int j = 0; j < 8; ++j) acc += q[j] * (float)v[j];
        sc[5 + a] = acc;
    }

    #pragma unroll
    for (int i = 0; i < 10; ++i) {
        sc[i] += __shfl_xor(sc[i], 8);
        sc[i] += __shfl_xor(sc[i], 16);
        sc[i] += __shfl_xor(sc[i], 32);
        sc[i] *= 0.125f;                   // 1/sqrt(64)
    }

    float mx = sc[0];
    #pragma unroll
    for (int i = 1; i < 10; ++i) mx = fmaxf(mx, sc[i]);
    float e[10], sum = 0.f;
    #pragma unroll
    for (int i = 0; i < 10; ++i) { e[i] = __expf(sc[i] - mx); sum += e[i]; }
    const float inv = 1.f / sum;

    float o[8];
    #pragma unroll
    for (int i = 0; i < 8; ++i) o[i] = 0.f;

    #pragma unroll
    for (int w = 0; w < 5; ++w) {
        const int lw = l + w - 2;
        if ((unsigned)lw < L_SEQ) {
            const bf16x8 v = *(const bf16x8*)(KVt + (size_t)(n + w - 2) * KVLD + 768 + c0);
            #pragma unroll
            for (int j = 0; j < 8; ++j) o[j] += e[w] * (float)v[j];
        }
    }
    #pragma unroll
    for (int a = 0; a < 5; ++a) {
        const bf16x8 v = *(const bf16x8*)(KVt + ((size_t)(a + 1) * NX + n) * KVLD + 768 + c0);
        #pragma unroll
        for (int j = 0; j < 8; ++j) o[j] += e[5 + a] * (float)v[j];
    }

    bf16x8 t;
    #pragma unroll
    for (int j = 0; j < 8; ++j) t[j] = (__bf16)(o[j] * inv);
    *(bf16x8*)(attT + (size_t)n * KD + c0) = t;
}

extern "C" void kernel_launch(void* const* d_in, const int* in_sizes, int n_in,
                              void* d_out, int out_size, void* d_ws, size_t ws_size,
                              hipStream_t stream)
{
    const float* x  = (const float*)d_in[0];
    const float* ax = (const float*)d_in[1];
    const float* Wq = (const float*)d_in[2];
    const float* bq = (const float*)d_in[3];
    const float* Wk = (const float*)d_in[4];
    const float* bk = (const float*)d_in[5];
    const float* Wv = (const float*)d_in[6];
    const float* bv = (const float*)d_in[7];
    const float* Wo = (const float*)d_in[8];
    const float* bo = (const float*)d_in[9];
    float* out = (float*)d_out;

    __bf16* p = (__bf16*)d_ws;
    __bf16* Wq_bf = p; p += 589824;
    __bf16* Wkv_bf = p;                       // [Wk_bf; Wv_bf] contiguous
    __bf16* Wk_bf = p; p += 589824;
    __bf16* Wv_bf = p; p += 589824;
    __bf16* Wo_bf = p; p += 589824;
    __bf16* Qt    = p; p += (size_t)KD * NX;
    __bf16* KVt   = p; p += (size_t)KVLD * NALL;
    __bf16* XT    = p; p += (size_t)KD * NALL;
    __bf16* attT  = p;

    // xconv (y 0..11) + weight conversion (y == 12) in one launch
    xconv_kernel<<<dim3(768, 13), dim3(256), 0, stream>>>(
        x, ax, XT, Wq, Wk, Wv, Wo, Wq_bf, Wk_bf, Wv_bf, Wo_bf);

    // merged Q|K|V: 64 n-tiles x 18 slots + 320 n-tiles x 12 slots = 4992 blocks
    gemm_qkv<<<dim3(4992), dim3(256), 0, stream>>>(Wq_bf, Wkv_bf, bq, bk, bv, XT, Qt, KVt);

    attn_kernel<<<dim3(3072), dim3(256), 0, stream>>>(Qt, KVt, attT);

    // O: fp32 final out, 6 m x 64 n = 384 blocks
    gemm_o<<<dim3(384), dim3(256), 0, stream>>>(Wo_bf, bo, attT, out);
}